// Round 9
// baseline (2250.586 us; speedup 1.0000x reference)
//
#include <hip/hip_runtime.h>
#include <hip/hip_bf16.h>
#include <hip/hip_cooperative_groups.h>
#include <math.h>

namespace cg = cooperative_groups;

#define L_TOK 1569
#define DM 192
#define DI 384
#define DS 16
#define DTR 12
#define DCONV 4
#define XDBL_N (DTR + 2*DS)   // 44
#define DEPTH 8
#define NCHUNK 25
#define CLEN 64
#define NPATCH 1568
#define NDG 24                // d-groups (384/16)

typedef __attribute__((ext_vector_type(8))) short short8;
typedef __attribute__((ext_vector_type(4))) float f32x4;

__device__ __forceinline__ unsigned short f2bf(float f) {
  unsigned int u = __float_as_uint(f);
  u += 0x7FFFu + ((u >> 16) & 1u);   // round-to-nearest-even
  return (unsigned short)(u >> 16);
}

struct KParams {
  const float *x, *patch_w, *patch_b, *cls_tok, *pos_emb;
  const float *ln_g, *ln_b, *W_in, *Wc, *bc, *Wx, *W_dt, *b_dt;
  const float *A_log, *Dp, *W_out, *fn_g, *fn_b;
  float *cur, *xz, *xdbl, *yy, *uc, *dlt, *cP, *cS, *out;
};

// ---- shared-memory union: one allocation reused by every phase -----------
struct LnxzS { unsigned short As[64][200]; unsigned short Bs[64][200];
               float gs[192]; float bs2[192]; };                  // 52.7 KB
struct GemmS { unsigned short As[64*40]; unsigned short Bs[64*40];
               float wcs[32][4]; float bcs[32]; };                // 10.9 KB
struct P1S   { float us[CLEN][16], ds[CLEN][16], bs[CLEN][16];
               float xd12[CLEN][12], wdt[16][12], bds[16]; };     // 16 KB
struct P3S   { float us[CLEN][16], ds[CLEN][16], bs[CLEN][16];
               float cs[CLEN][16], zs[CLEN][16]; };               // 20 KB
union SmemU { LnxzS ln; GemmS g; P1S p1; P3S p3; };

// ---------------------------------------------------------------------------
// Phase: im2col + cur init (pos + bias/cls). vb in [0, 1176).
// ---------------------------------------------------------------------------
__device__ __forceinline__ void ph_im2col(const KParams& P, int vb) {
  float* px = P.xz;   // im2col buffer aliases xz (dead before layer-0 xz)
  int gid = vb * 256 + threadIdx.x;
  const int initN = (L_TOK * DM) / 4;   // 75312 float4s
  if (gid < initN) {
    int e4 = gid * 4;
    int tok = e4 / DM;
    int col = e4 % DM;
    float4 pv = *(const float4*)(P.pos_emb + e4);
    float4 av = (tok == 0) ? *(const float4*)(P.cls_tok + col)
                           : *(const float4*)(P.patch_b + col);
    float4 o = {pv.x + av.x, pv.y + av.y, pv.z + av.z, pv.w + av.w};
    *(float4*)(P.cur + e4) = o;
  }
  if (gid < NPATCH * 192) {
    int patch = gid / 192;
    int r = gid % 192;
    int c = r / 64;
    int p = (r >> 2) & 15;
    int q = (r & 3) * 4;
    int t = patch / 196, hw = patch % 196, hh = hw / 14, w = hw % 14;
    const float* src = P.x + ((size_t)(c*8 + t)*224 + hh*16 + p)*224 + w*16 + q;
    *(float4*)(px + (size_t)patch*768 + r*4) = *(const float4*)src;
  }
}

// ---------------------------------------------------------------------------
// Phase: MFMA bf16 GEMM tile with split-K; always atomicAdd (C pre-init).
// ---------------------------------------------------------------------------
__device__ __forceinline__ void ph_mgemm(SmemU& S,
    const float* __restrict__ A, int lda,
    const float* __restrict__ B, int ldb,
    float* __restrict__ C, int ldc,
    int M, int N, int ksl, int bx, int by, int bz) {
  int tid = threadIdx.x;
  int m0 = by * 64, n0 = bx * 64;
  int kbase = bz * ksl;
  int wave = tid >> 6, lane = tid & 63;
  int wr = wave >> 1, wc = wave & 1;
  int srow = tid >> 2;
  int skq  = (tid & 3) * 8;
  f32x4 acc[2][2];
#pragma unroll
  for (int i = 0; i < 2; ++i)
#pragma unroll
    for (int j = 0; j < 2; ++j) acc[i][j] = (f32x4){0.f,0.f,0.f,0.f};

  int am = m0 + srow;
  int bn = n0 + srow;
  bool a_ok = (am < M), b_ok = (bn < N);
  const float* ap = A + (size_t)am*lda + kbase + skq;
  const float* bp = B + (size_t)bn*ldb + kbase + skq;
  const float4 z4 = {0.f,0.f,0.f,0.f};
  int l15 = lane & 15, lk = (lane >> 4) * 8;

  int nt = ksl >> 5;
  float4 a0 = a_ok ? *(const float4*)(ap)     : z4;
  float4 a1 = a_ok ? *(const float4*)(ap + 4) : z4;
  float4 b0 = b_ok ? *(const float4*)(bp)     : z4;
  float4 b1 = b_ok ? *(const float4*)(bp + 4) : z4;

  for (int i = 0; i < nt; ++i) {
    {
      short8 pa, pb;
      pa[0]=f2bf(a0.x); pa[1]=f2bf(a0.y); pa[2]=f2bf(a0.z); pa[3]=f2bf(a0.w);
      pa[4]=f2bf(a1.x); pa[5]=f2bf(a1.y); pa[6]=f2bf(a1.z); pa[7]=f2bf(a1.w);
      pb[0]=f2bf(b0.x); pb[1]=f2bf(b0.y); pb[2]=f2bf(b0.z); pb[3]=f2bf(b0.w);
      pb[4]=f2bf(b1.x); pb[5]=f2bf(b1.y); pb[6]=f2bf(b1.z); pb[7]=f2bf(b1.w);
      *(short8*)&S.g.As[srow*40 + skq] = pa;
      *(short8*)&S.g.Bs[srow*40 + skq] = pb;
    }
    __syncthreads();
    bool pf = (i + 1 < nt);
    int k0n = (i + 1) << 5;
    a0 = (pf && a_ok) ? *(const float4*)(ap + k0n)     : z4;
    a1 = (pf && a_ok) ? *(const float4*)(ap + k0n + 4) : z4;
    b0 = (pf && b_ok) ? *(const float4*)(bp + k0n)     : z4;
    b1 = (pf && b_ok) ? *(const float4*)(bp + k0n + 4) : z4;

    short8 af0 = *(const short8*)&S.g.As[(wr*32      + l15)*40 + lk];
    short8 af1 = *(const short8*)&S.g.As[(wr*32 + 16 + l15)*40 + lk];
    short8 bf0 = *(const short8*)&S.g.Bs[(wc*32      + l15)*40 + lk];
    short8 bf1 = *(const short8*)&S.g.Bs[(wc*32 + 16 + l15)*40 + lk];
    acc[0][0] = __builtin_amdgcn_mfma_f32_16x16x32_bf16(af0, bf0, acc[0][0], 0, 0, 0);
    acc[0][1] = __builtin_amdgcn_mfma_f32_16x16x32_bf16(af0, bf1, acc[0][1], 0, 0, 0);
    acc[1][0] = __builtin_amdgcn_mfma_f32_16x16x32_bf16(af1, bf0, acc[1][0], 0, 0, 0);
    acc[1][1] = __builtin_amdgcn_mfma_f32_16x16x32_bf16(af1, bf1, acc[1][1], 0, 0, 0);
    __syncthreads();
  }

#pragma unroll
  for (int r = 0; r < 2; ++r) {
#pragma unroll
    for (int c = 0; c < 2; ++c) {
      int col = n0 + wc*32 + c*16 + l15;
      if (col >= N) continue;
      int rowb = m0 + wr*32 + r*16 + (lane >> 4)*4;
#pragma unroll
      for (int j = 0; j < 4; ++j) {
        int row = rowb + j;
        if (row >= M) continue;
        atomicAdd(C + (size_t)row*ldc + col, acc[r][c][j]);
      }
    }
  }
  __syncthreads();   // protect LDS before next vb iteration
}

// ---------------------------------------------------------------------------
// Phase: fused LN + xz GEMM (K=192 in LDS, one barrier before 6 MFMA k-steps).
// bx==0 blocks also zero xdbl rows for the atomic cgemm downstream.
// ---------------------------------------------------------------------------
__device__ __forceinline__ void ph_lnxz(SmemU& S,
    const float* __restrict__ cur, const float* __restrict__ g,
    const float* __restrict__ b, const float* __restrict__ W,
    float* __restrict__ xz, float* __restrict__ xdbl_z, int bx, int by) {
  int tid = threadIdx.x;
  int m0 = by * 64, n0 = bx * 64;
  int wave = tid >> 6, lane = tid & 63;
  int wr = wave >> 1, wc = wave & 1;
  int l15 = lane & 15, lk = (lane >> 4) * 8;

  for (int i = tid; i < 192; i += 256) { S.ln.gs[i] = g[i]; S.ln.bs2[i] = b[i]; }

  if (bx == 0) {
    for (int i = tid; i < 64*11; i += 256) {
      int r = i / 11, q = i % 11;
      int row = m0 + r;
      if (row < L_TOK) {
        float4 z = {0.f,0.f,0.f,0.f};
        *(float4*)(xdbl_z + (size_t)row*XDBL_N + q*4) = z;
      }
    }
  }

  int r = tid >> 2, c0 = (tid & 3) * 48;
  float v[48];
  {
    int row = m0 + r;
    if (row < L_TOK) {
      const float* rp = cur + (size_t)row*DM + c0;
#pragma unroll
      for (int j = 0; j < 12; ++j) {
        float4 t4 = *(const float4*)(rp + j*4);
        v[j*4+0]=t4.x; v[j*4+1]=t4.y; v[j*4+2]=t4.z; v[j*4+3]=t4.w;
      }
    } else {
#pragma unroll
      for (int j = 0; j < 48; ++j) v[j] = 0.f;
    }
  }
  float s = 0.f, s2 = 0.f;
#pragma unroll
  for (int j = 0; j < 48; ++j) { s += v[j]; s2 += v[j]*v[j]; }
  s  += __shfl_xor(s, 1, 64); s2 += __shfl_xor(s2, 1, 64);
  s  += __shfl_xor(s, 2, 64); s2 += __shfl_xor(s2, 2, 64);
  float mu = s * (1.0f/192.0f);
  float var = s2 * (1.0f/192.0f) - mu*mu;
  float rsd = rsqrtf(var + 1e-5f);

  __syncthreads();   // gs/bs2 ready
#pragma unroll
  for (int j = 0; j < 48; ++j) {
    int k = c0 + j;
    S.ln.As[r][k] = f2bf((v[j] - mu)*rsd*S.ln.gs[k] + S.ln.bs2[k]);
  }
  {
    const float* rp = W + (size_t)(n0 + r)*DM + c0;
#pragma unroll
    for (int j = 0; j < 12; ++j) {
      float4 t4 = *(const float4*)(rp + j*4);
      S.ln.Bs[r][c0+j*4+0]=f2bf(t4.x); S.ln.Bs[r][c0+j*4+1]=f2bf(t4.y);
      S.ln.Bs[r][c0+j*4+2]=f2bf(t4.z); S.ln.Bs[r][c0+j*4+3]=f2bf(t4.w);
    }
  }
  __syncthreads();

  f32x4 acc[2][2];
#pragma unroll
  for (int i = 0; i < 2; ++i)
#pragma unroll
    for (int j = 0; j < 2; ++j) acc[i][j] = (f32x4){0.f,0.f,0.f,0.f};

#pragma unroll
  for (int kk = 0; kk < 6; ++kk) {
    short8 af0 = *(const short8*)&S.ln.As[wr*32      + l15][kk*32 + lk];
    short8 af1 = *(const short8*)&S.ln.As[wr*32 + 16 + l15][kk*32 + lk];
    short8 bf0 = *(const short8*)&S.ln.Bs[wc*32      + l15][kk*32 + lk];
    short8 bf1 = *(const short8*)&S.ln.Bs[wc*32 + 16 + l15][kk*32 + lk];
    acc[0][0] = __builtin_amdgcn_mfma_f32_16x16x32_bf16(af0, bf0, acc[0][0], 0, 0, 0);
    acc[0][1] = __builtin_amdgcn_mfma_f32_16x16x32_bf16(af0, bf1, acc[0][1], 0, 0, 0);
    acc[1][0] = __builtin_amdgcn_mfma_f32_16x16x32_bf16(af1, bf0, acc[1][0], 0, 0, 0);
    acc[1][1] = __builtin_amdgcn_mfma_f32_16x16x32_bf16(af1, bf1, acc[1][1], 0, 0, 0);
  }

#pragma unroll
  for (int rr = 0; rr < 2; ++rr) {
#pragma unroll
    for (int cc = 0; cc < 2; ++cc) {
      int col = n0 + wc*32 + cc*16 + l15;
      int rowb = m0 + wr*32 + rr*16 + (lane >> 4)*4;
#pragma unroll
      for (int j = 0; j < 4; ++j) {
        int row = rowb + j;
        if (row < L_TOK) xz[(size_t)row*(2*DI) + col] = acc[rr][cc][j];
      }
    }
  }
  __syncthreads();
}

// ---------------------------------------------------------------------------
// Phase: xdbl GEMM, conv+SiLU fused in A-staging; split-K 12 (one k-step).
// Exports u = silu(conv(xz)) to uc. xdbl pre-zeroed by lnxz.
// ---------------------------------------------------------------------------
__device__ __forceinline__ void ph_cgemm(SmemU& S,
    const float* __restrict__ xz,
    const float* __restrict__ Wc, const float* __restrict__ bc,
    const float* __restrict__ B, float* __restrict__ C,
    float* __restrict__ uc, int by, int bz) {
  const int M = L_TOK, N = XDBL_N;
  int tid = threadIdx.x;
  int m0 = by * 64;
  int kbase = bz * 32;
  int wave = tid >> 6, lane = tid & 63;
  int wr = wave >> 1, wcq = wave & 1;
  int srow = tid >> 2;
  int skq  = (tid & 3) * 8;
  if (tid < 32) {
    *(float4*)S.g.wcs[tid] = *(const float4*)(Wc + (size_t)(kbase + tid)*4);
    S.g.bcs[tid] = bc[kbase + tid];
  }

  int t = m0 + srow;
  bool a_ok = (t < M);
  bool b_ok = (srow < N);
  const float* bp = B + (size_t)srow*DI + kbase + skq;
  const float4 z4 = {0.f,0.f,0.f,0.f};
  int l15 = lane & 15, lk = (lane >> 4) * 8;
  int cg = kbase + skq;

  float tap[4][8];
#pragma unroll
  for (int j = 0; j < 4; ++j) {
    int ts = t - 3 + j;
    float4 v0 = z4, v1 = z4;
    if (a_ok && ts >= 0) {
      v0 = *(const float4*)(xz + (size_t)ts*(2*DI) + cg);
      v1 = *(const float4*)(xz + (size_t)ts*(2*DI) + cg + 4);
    }
    tap[j][0]=v0.x; tap[j][1]=v0.y; tap[j][2]=v0.z; tap[j][3]=v0.w;
    tap[j][4]=v1.x; tap[j][5]=v1.y; tap[j][6]=v1.z; tap[j][7]=v1.w;
  }
  float4 bv0 = b_ok ? *(const float4*)(bp)     : z4;
  float4 bv1 = b_ok ? *(const float4*)(bp + 4) : z4;
  __syncthreads();   // wcs/bcs ready

  float uv[8];
  short8 pa, pb;
#pragma unroll
  for (int c = 0; c < 8; ++c) {
    float u = S.g.bcs[skq + c];
#pragma unroll
    for (int j = 0; j < 4; ++j) u = fmaf(tap[j][c], S.g.wcs[skq + c][j], u);
    u = u / (1.0f + expf(-u));
    uv[c] = u;
    pa[c] = (short)f2bf(u);
  }
  if (a_ok) {
    float4 o0 = {uv[0], uv[1], uv[2], uv[3]};
    float4 o1 = {uv[4], uv[5], uv[6], uv[7]};
    *(float4*)(uc + (size_t)t*DI + cg)     = o0;
    *(float4*)(uc + (size_t)t*DI + cg + 4) = o1;
  }
  pb[0]=f2bf(bv0.x); pb[1]=f2bf(bv0.y); pb[2]=f2bf(bv0.z); pb[3]=f2bf(bv0.w);
  pb[4]=f2bf(bv1.x); pb[5]=f2bf(bv1.y); pb[6]=f2bf(bv1.z); pb[7]=f2bf(bv1.w);
  *(short8*)&S.g.As[srow*40 + skq] = pa;
  *(short8*)&S.g.Bs[srow*40 + skq] = pb;
  __syncthreads();

  f32x4 acc[2][2];
#pragma unroll
  for (int i = 0; i < 2; ++i)
#pragma unroll
    for (int j = 0; j < 2; ++j) acc[i][j] = (f32x4){0.f,0.f,0.f,0.f};
  short8 af0 = *(const short8*)&S.g.As[(wr*32      + l15)*40 + lk];
  short8 af1 = *(const short8*)&S.g.As[(wr*32 + 16 + l15)*40 + lk];
  short8 bf0 = *(const short8*)&S.g.Bs[(wcq*32      + l15)*40 + lk];
  short8 bf1 = *(const short8*)&S.g.Bs[(wcq*32 + 16 + l15)*40 + lk];
  acc[0][0] = __builtin_amdgcn_mfma_f32_16x16x32_bf16(af0, bf0, acc[0][0], 0, 0, 0);
  acc[0][1] = __builtin_amdgcn_mfma_f32_16x16x32_bf16(af0, bf1, acc[0][1], 0, 0, 0);
  acc[1][0] = __builtin_amdgcn_mfma_f32_16x16x32_bf16(af1, bf0, acc[1][0], 0, 0, 0);
  acc[1][1] = __builtin_amdgcn_mfma_f32_16x16x32_bf16(af1, bf1, acc[1][1], 0, 0, 0);

#pragma unroll
  for (int r = 0; r < 2; ++r) {
#pragma unroll
    for (int c = 0; c < 2; ++c) {
      int col = wcq*32 + c*16 + l15;
      if (col >= N) continue;
      int rowb = m0 + wr*32 + r*16 + (lane >> 4)*4;
#pragma unroll
      for (int j = 0; j < 4; ++j) {
        int row = rowb + j;
        if (row >= M) continue;
        atomicAdd(C + (size_t)row*XDBL_N + col, acc[r][c][j]);
      }
    }
  }
  __syncthreads();
}

// ---------------------------------------------------------------------------
// Phase: scan p1 — per-chunk local scan from zero state; exports delta.
// ---------------------------------------------------------------------------
__device__ __forceinline__ void ph_p1(SmemU& S,
    const float* __restrict__ uc, const float* __restrict__ xdbl,
    const float* __restrict__ W_dt, const float* __restrict__ b_dt,
    const float* __restrict__ A_log,
    float* __restrict__ cP, float* __restrict__ cS,
    float* __restrict__ dlt, int bx, int by) {
  int tid = threadIdx.x;
  int dl = tid >> 4, n = tid & 15;
  int d0 = bx * 16;
  int t0 = by * CLEN;
  int nt = min(CLEN, L_TOK - t0);

  for (int i = tid; i < CLEN*16; i += 256) {
    int tt = i >> 4, dd = i & 15;
    int t = t0 + tt;
    S.p1.us[tt][dd] = (t < L_TOK) ? uc[(size_t)t*DI + d0 + dd] : 0.0f;
  }
  for (int i = tid; i < CLEN*28; i += 256) {
    int tt = i / 28, c = i % 28;
    int t = t0 + tt;
    float v = (t < L_TOK) ? xdbl[(size_t)t*XDBL_N + c] : 0.0f;
    if (c < 12) S.p1.xd12[tt][c] = v;
    else S.p1.bs[tt][c-12] = v;
  }
  if (tid < 192) S.p1.wdt[tid/12][tid%12] = W_dt[(d0 + tid/12)*DTR + tid%12];
  if (tid < 16)  S.p1.bds[tid] = b_dt[d0+tid];
  __syncthreads();
  for (int i = tid; i < CLEN*16; i += 256) {
    int tt = i >> 4, dd = i & 15;
    float v = S.p1.bds[dd];
#pragma unroll
    for (int r = 0; r < 12; ++r) v = fmaf(S.p1.xd12[tt][r], S.p1.wdt[dd][r], v);
    v = (v > 20.0f) ? v : log1pf(expf(v));
    S.p1.ds[tt][dd] = v;
    int t = t0 + tt;
    if (t < L_TOK) dlt[(size_t)t*DI + d0 + dd] = v;
  }
  __syncthreads();

  int d = d0 + dl;
  float a2 = -expf(A_log[d*DS + n]) * 1.44269504088896340736f;
  float s = 0.0f, Pk = 1.0f;
  for (int tt = 0; tt < nt; ++tt) {
    float dv = S.p1.ds[tt][dl];
    float dA = exp2f(dv * a2);
    s = fmaf(dA, s, dv * S.p1.bs[tt][n] * S.p1.us[tt][dl]);
    Pk *= dA;
  }
  int o = (by * DI + d) * DS + n;
  cP[o] = Pk;
  cS[o] = s;
  __syncthreads();
}

// ---------------------------------------------------------------------------
// Phase: scan p3 — carry-in combine over preceding chunks, re-scan, emit y.
// ---------------------------------------------------------------------------
__device__ __forceinline__ void ph_p3(SmemU& S,
    const float* __restrict__ uc, const float* __restrict__ dlt,
    const float* __restrict__ xdbl, const float* __restrict__ xz,
    const float* __restrict__ A_log, const float* __restrict__ Dp,
    const float* __restrict__ cP, const float* __restrict__ cS,
    float* __restrict__ yy, int bx, int by) {
  int tid = threadIdx.x;
  int dl = tid >> 4, n = tid & 15;
  int d0 = bx * 16;
  int cidx = by;
  int t0 = cidx * CLEN;
  int nt = min(CLEN, L_TOK - t0);
  int d = d0 + dl;

  float s = 0.0f;
  {
    int oo = d * DS + n;
#pragma unroll 4
    for (int c2 = 0; c2 < cidx; ++c2) {
      s = fmaf(cP[(size_t)c2*(DI*DS) + oo], s, cS[(size_t)c2*(DI*DS) + oo]);
    }
  }

  for (int i = tid; i < CLEN*16; i += 256) {
    int tt = i >> 4, dd = i & 15;
    int t = t0 + tt;
    bool ok = (t < L_TOK);
    S.p3.us[tt][dd] = ok ? uc[(size_t)t*DI + d0 + dd] : 0.0f;
    S.p3.ds[tt][dd] = ok ? dlt[(size_t)t*DI + d0 + dd] : 0.0f;
    S.p3.zs[tt][dd] = ok ? xz[(size_t)t*(2*DI) + DI + d0 + dd] : 0.0f;
  }
  for (int i = tid; i < CLEN*32; i += 256) {
    int tt = i >> 5, c = i & 31;
    int t = t0 + tt;
    float v = (t < L_TOK) ? xdbl[(size_t)t*XDBL_N + 12 + c] : 0.0f;
    if (c < 16) S.p3.bs[tt][c] = v;
    else S.p3.cs[tt][c-16] = v;
  }
  __syncthreads();

  float a2 = -expf(A_log[d*DS + n]) * 1.44269504088896340736f;
  float dpv = Dp[d];
  for (int tt = 0; tt < nt; ++tt) {
    float dv = S.p3.ds[tt][dl], uu = S.p3.us[tt][dl];
    float dA = exp2f(dv * a2);
    s = fmaf(dA, s, dv * S.p3.bs[tt][n] * uu);
    float p = s * S.p3.cs[tt][n];
    p += __shfl_xor(p, 1, 64);
    p += __shfl_xor(p, 2, 64);
    p += __shfl_xor(p, 4, 64);
    p += __shfl_xor(p, 8, 64);
    if (n == 0) {
      float z = S.p3.zs[tt][dl];
      float y = fmaf(uu, dpv, p);
      y *= z / (1.0f + expf(-z));
      yy[(size_t)(t0 + tt)*DI + d] = y;
    }
  }
  __syncthreads();
}

// ---------------------------------------------------------------------------
// Phase: final LayerNorm, 4 tokens per 256-thread block (1 wave each).
// ---------------------------------------------------------------------------
__device__ __forceinline__ void ph_lnfinal(const KParams& P, int vb) {
  int tok = vb*4 + (threadIdx.x >> 6);
  int lane = threadIdx.x & 63;
  if (tok < L_TOK) {
    const float* row = P.cur + (size_t)tok*DM;
    float x0 = row[lane], x1 = row[lane+64], x2 = row[lane+128];
    float s = x0 + x1 + x2;
    float s2 = x0*x0 + x1*x1 + x2*x2;
#pragma unroll
    for (int off = 1; off < 64; off <<= 1) {
      s  += __shfl_xor(s,  off, 64);
      s2 += __shfl_xor(s2, off, 64);
    }
    float m = s * (1.0f/192.0f);
    float v = s2 * (1.0f/192.0f) - m*m;
    float rs = rsqrtf(v + 1e-5f);
    float* orow = P.out + (size_t)tok*DM;
    orow[lane]     = (x0 - m)*rs*P.fn_g[lane]     + P.fn_b[lane];
    orow[lane+64]  = (x1 - m)*rs*P.fn_g[lane+64]  + P.fn_b[lane+64];
    orow[lane+128] = (x2 - m)*rs*P.fn_g[lane+128] + P.fn_b[lane+128];
  }
}

// ---------------------------------------------------------------------------
// The single cooperative kernel: every phase, grid.sync() between them.
// ---------------------------------------------------------------------------
__global__ __launch_bounds__(256, 2) void fused_all(KParams P) {
  cg::grid_group grid = cg::this_grid();
  __shared__ SmemU S;
  const int GB = gridDim.x;

  for (int vb = blockIdx.x; vb < 1176; vb += GB) ph_im2col(P, vb);
  grid.sync();

  // patch GEMM: cur[1..] += px @ patch_w^T (M=1568, N=192, K=768, split-K 4)
  for (int vb = blockIdx.x; vb < 300; vb += GB)
    ph_mgemm(S, P.xz, 768, P.patch_w, 768, P.cur + DM, DM,
             NPATCH, DM, 192, vb % 3, (vb / 3) % 25, vb / 75);
  grid.sync();

  for (int dep = 0; dep < DEPTH; ++dep) {
    const float* g     = P.ln_g  + dep*DM;
    const float* bb    = P.ln_b  + dep*DM;
    const float* Win_l = P.W_in  + (size_t)dep*2*DI*DM;
    const float* Wc_l  = P.Wc    + (size_t)dep*DI*DCONV;
    const float* bc_l  = P.bc    + (size_t)dep*DI;
    const float* Wx_l  = P.Wx    + (size_t)dep*XDBL_N*DI;
    const float* Wdt_l = P.W_dt  + (size_t)dep*DI*DTR;
    const float* bdt_l = P.b_dt  + (size_t)dep*DI;
    const float* Alog_l= P.A_log + (size_t)dep*DI*DS;
    const float* Dp_l  = P.Dp    + (size_t)dep*DI;
    const float* Wout_l= P.W_out + (size_t)dep*DM*DI;

    for (int vb = blockIdx.x; vb < 300; vb += GB)
      ph_lnxz(S, P.cur, g, bb, Win_l, P.xz, P.xdbl, vb % 12, vb / 12);
    grid.sync();

    for (int vb = blockIdx.x; vb < 300; vb += GB)
      ph_cgemm(S, P.xz, Wc_l, bc_l, Wx_l, P.xdbl, P.uc, vb % 25, vb / 25);
    grid.sync();

    for (int vb = blockIdx.x; vb < NDG*NCHUNK; vb += GB)
      ph_p1(S, P.uc, P.xdbl, Wdt_l, bdt_l, Alog_l, P.cP, P.cS, P.dlt,
            vb % NDG, vb / NDG);
    grid.sync();

    for (int vb = blockIdx.x; vb < NDG*NCHUNK; vb += GB)
      ph_p3(S, P.uc, P.dlt, P.xdbl, P.xz, Alog_l, Dp_l, P.cP, P.cS, P.yy,
            vb % NDG, vb / NDG);
    grid.sync();

    // cur += yy @ W_out^T (M=1569, N=192, K=384, split-K 4)
    for (int vb = blockIdx.x; vb < 300; vb += GB)
      ph_mgemm(S, P.yy, DI, Wout_l, DI, P.cur, DM,
               L_TOK, DM, 96, vb % 3, (vb / 3) % 25, vb / 75);
    grid.sync();
  }

  for (int vb = blockIdx.x; vb < (L_TOK + 3)/4; vb += GB) ph_lnfinal(P, vb);
}

// ---------------------------------------------------------------------------
extern "C" void kernel_launch(void* const* d_in, const int* in_sizes, int n_in,
                              void* d_out, int out_size, void* d_ws, size_t ws_size,
                              hipStream_t stream) {
  float* ws = (float*)d_ws;
  float* cur   = ws;                       // 1569*192
  float* xz    = cur   + L_TOK*DM;         // 1569*768 (aliases px)
  float* xdbl  = xz    + L_TOK*2*DI;       // 1569*44
  float* yy    = xdbl  + L_TOK*XDBL_N;     // 1569*384
  float* uc    = yy    + L_TOK*DI;         // 1569*384
  float* dlt   = uc    + L_TOK*DI;         // 1569*384
  float* cP    = dlt   + L_TOK*DI;         // 25*6144
  float* cS    = cP    + NCHUNK*DI*DS;

  KParams P;
  P.x       = (const float*)d_in[0];
  P.patch_w = (const float*)d_in[1];
  P.patch_b = (const float*)d_in[2];
  P.cls_tok = (const float*)d_in[3];
  P.pos_emb = (const float*)d_in[4];
  P.ln_g    = (const float*)d_in[5];
  P.ln_b    = (const float*)d_in[6];
  P.W_in    = (const float*)d_in[7];
  P.Wc      = (const float*)d_in[8];
  P.bc      = (const float*)d_in[9];
  P.Wx      = (const float*)d_in[10];
  P.W_dt    = (const float*)d_in[11];
  P.b_dt    = (const float*)d_in[12];
  P.A_log   = (const float*)d_in[13];
  P.Dp      = (const float*)d_in[14];
  P.W_out   = (const float*)d_in[15];
  P.fn_g    = (const float*)d_in[16];
  P.fn_b    = (const float*)d_in[17];
  P.cur = cur; P.xz = xz; P.xdbl = xdbl; P.yy = yy;
  P.uc = uc; P.dlt = dlt; P.cP = cP; P.cS = cS;
  P.out = (float*)d_out;

  // Size the cooperative grid from occupancy (deterministic each call).
  int dev = 0;
  hipGetDevice(&dev);
  int ncu = 0;
  hipDeviceGetAttribute(&ncu, hipDeviceAttributeMultiprocessorCount, dev);
  if (ncu < 1) ncu = 256;
  int bpc = 0;
  hipOccupancyMaxActiveBlocksPerMultiprocessor(&bpc, fused_all, 256, 0);
  if (bpc < 1) bpc = 1;
  int gsz = bpc * ncu;
  if (gsz > 512) gsz = 512;

  void* args[] = { &P };
  hipLaunchCooperativeKernel((void*)fused_all, dim3(gsz), dim3(256),
                             args, 0, stream);
}